// Round 1
// baseline (468.435 us; speedup 1.0000x reference)
//
#include <hip/hip_runtime.h>

#define NROWS 65536
#define KDIM  512
constexpr float BN_EPS = 1e-5f;

// ---------------- Kernel 1: quad[n] = x_n^T C1 x_n ----------------
// Tiled fp32 GEMM (X @ C1) fused with row-dot epilogue against X.
// Block: 128 rows, 256 threads (ty=tid/16, tx=tid%15). j in 4 tiles of 128,
// k in 16 tiles of 32. Thread tile 8 rows x 8 cols (split 2x4 + 2x4 for
// conflict-free float4 LDS reads: rows {4ty+i, 64+4ty+i}, cols {4tx+u, 64+4tx+u}).

#define BM 128
#define BJ 128
#define BK 32

__global__ __launch_bounds__(256)
void quad_kernel(const float* __restrict__ X, const float* __restrict__ C1,
                 float* __restrict__ quad) {
  __shared__ float Xs[BK][BM + 4];   // transposed: Xs[k][row], pad keeps 16B align + spreads banks
  __shared__ float C1s[BK][BJ];

  const int tid = threadIdx.x;
  const int ty = tid >> 4;
  const int tx = tid & 15;
  const int r0 = blockIdx.x * BM;

  float qacc[2][4] = {};

  for (int jt = 0; jt < KDIM / BJ; ++jt) {
    const int j0 = jt * BJ;
    float acc[2][4][2][4] = {};   // [ri][i][ci][u]
    for (int kt = 0; kt < KDIM / BK; ++kt) {
      const int k0 = kt * BK;
      // stage X tile (transposed): 128 rows x 32 k
      #pragma unroll
      for (int w = 0; w < 4; ++w) {
        const int f = tid + w * 256;      // 0..1023
        const int row = f >> 3;           // 0..127
        const int kq = f & 7;             // 0..7
        const float4 v = *(const float4*)&X[(size_t)(r0 + row) * KDIM + k0 + kq * 4];
        Xs[kq * 4 + 0][row] = v.x;
        Xs[kq * 4 + 1][row] = v.y;
        Xs[kq * 4 + 2][row] = v.z;
        Xs[kq * 4 + 3][row] = v.w;
      }
      // stage C1 tile: 32 k x 128 j (row-major, dense float4 writes)
      #pragma unroll
      for (int w = 0; w < 4; ++w) {
        const int f = tid + w * 256;
        const int kr = f >> 5;            // 0..31
        const int jq = f & 31;            // 0..31
        *(float4*)&C1s[kr][jq * 4] =
            *(const float4*)&C1[(size_t)(k0 + kr) * KDIM + j0 + jq * 4];
      }
      __syncthreads();
      #pragma unroll 8
      for (int kk = 0; kk < BK; ++kk) {
        const float4 xa = *(const float4*)&Xs[kk][4 * ty];
        const float4 xb = *(const float4*)&Xs[kk][64 + 4 * ty];
        const float4 ca = *(const float4*)&C1s[kk][4 * tx];
        const float4 cb = *(const float4*)&C1s[kk][64 + 4 * tx];
        const float xr[2][4] = {{xa.x, xa.y, xa.z, xa.w}, {xb.x, xb.y, xb.z, xb.w}};
        const float cr[2][4] = {{ca.x, ca.y, ca.z, ca.w}, {cb.x, cb.y, cb.z, cb.w}};
        #pragma unroll
        for (int ri = 0; ri < 2; ++ri)
          #pragma unroll
          for (int i = 0; i < 4; ++i)
            #pragma unroll
            for (int ci = 0; ci < 2; ++ci)
              #pragma unroll
              for (int u = 0; u < 4; ++u)
                acc[ri][i][ci][u] = fmaf(xr[ri][i], cr[ci][u], acc[ri][i][ci][u]);
      }
      __syncthreads();
    }
    // epilogue for this j-tile: qacc += (X@C1)[row, j] * X[row, j]
    #pragma unroll
    for (int ri = 0; ri < 2; ++ri)
      #pragma unroll
      for (int i = 0; i < 4; ++i) {
        const int grow = r0 + ri * 64 + 4 * ty + i;
        const float* Xrow = X + (size_t)grow * KDIM + j0;
        #pragma unroll
        for (int ci = 0; ci < 2; ++ci) {
          const float4 xj = *(const float4*)&Xrow[ci * 64 + 4 * tx];
          qacc[ri][i] += acc[ri][i][ci][0] * xj.x + acc[ri][i][ci][1] * xj.y +
                         acc[ri][i][ci][2] * xj.z + acc[ri][i][ci][3] * xj.w;
        }
      }
  }
  // reduce across the 16 tx lanes (lanes sharing ty are contiguous 16-lane groups)
  #pragma unroll
  for (int ri = 0; ri < 2; ++ri)
    #pragma unroll
    for (int i = 0; i < 4; ++i) {
      float q = qacc[ri][i];
      #pragma unroll
      for (int m = 1; m < 16; m <<= 1) q += __shfl_xor(q, m, 64);
      if (tx == 0) quad[r0 + ri * 64 + 4 * ty + i] = q;
    }
}

// ---------------- Kernel 2: column sufficient statistics ----------------
// 256 blocks x 256 threads; block handles 256 rows; thread owns 2 columns.
__global__ __launch_bounds__(256)
void colstats_kernel(const float* __restrict__ X, const float* __restrict__ quad,
                     float* __restrict__ colS1, float* __restrict__ colS2,
                     float* __restrict__ colS3, double* __restrict__ qsums) {
  const int t = threadIdx.x;
  const int rbase = blockIdx.x * 256;
  float s1x = 0.f, s1y = 0.f, s2x = 0.f, s2y = 0.f, s3x = 0.f, s3y = 0.f;
  double qs = 0.0, qs2 = 0.0;
  for (int r = 0; r < 256; ++r) {
    const int row = rbase + r;
    const float q = quad[row];             // broadcast load
    qs += (double)q;
    qs2 += (double)q * (double)q;
    const float2 x = *(const float2*)&X[(size_t)row * KDIM + t * 2];
    s1x += x.x;          s1y += x.y;
    s2x += x.x * x.x;    s2y += x.y * x.y;
    s3x += q * x.x;      s3y += q * x.y;
  }
  atomicAdd(&colS1[t * 2 + 0], s1x); atomicAdd(&colS1[t * 2 + 1], s1y);
  atomicAdd(&colS2[t * 2 + 0], s2x); atomicAdd(&colS2[t * 2 + 1], s2y);
  atomicAdd(&colS3[t * 2 + 0], s3x); atomicAdd(&colS3[t * 2 + 1], s3y);
  if (t == 0) { atomicAdd(&qsums[0], qs); atomicAdd(&qsums[1], qs2); }
}

// ---------------- Kernel 3: finalize per-feature mean / inv_std ----------------
__global__ void finalize_kernel(const float* __restrict__ colS1, const float* __restrict__ colS2,
                                const float* __restrict__ colS3, const double* __restrict__ qsums,
                                const float* __restrict__ C2, const float* __restrict__ C3,
                                float* __restrict__ mean, float* __restrict__ inv_std) {
  const int k = blockIdx.x * blockDim.x + threadIdx.x;
  if (k >= KDIM) return;
  const double invN = 1.0 / (double)NROWS;
  const double meanQ = qsums[0] * invN;
  const double varQ  = qsums[1] * invN - meanQ * meanQ;
  const float meanX = colS1[k] * (float)invN;
  const float varX  = colS2[k] * (float)invN - meanX * meanX;
  const float covQX = colS3[k] * (float)invN - (float)meanQ * meanX;
  const float c2 = C2[k];
  const float c3 = C3[0];
  const float m = (float)meanQ + c2 * meanX + c3;
  const float v = (float)varQ + c2 * c2 * varX + 2.0f * c2 * covQX;
  mean[k] = m;
  inv_std[k] = 1.0f / sqrtf(v + BN_EPS);
}

// ---------------- Kernel 4: write normalized output ----------------
__global__ __launch_bounds__(256)
void normalize_kernel(const float* __restrict__ X, const float* __restrict__ quad,
                      const float* __restrict__ C2, const float* __restrict__ C3,
                      const float* __restrict__ mean, const float* __restrict__ inv_std,
                      float* __restrict__ out) {
  const int idx = blockIdx.x * blockDim.x + threadIdx.x;  // float4 index
  const int n = idx >> 7;                                 // KDIM/4 = 128 float4/row
  const int j4 = idx & 127;
  const float q = quad[n];
  const float c3 = C3[0];
  const float4 x  = *(const float4*)&X[(size_t)idx * 4];
  const float4 c2 = *(const float4*)&C2[j4 * 4];
  const float4 m  = *(const float4*)&mean[j4 * 4];
  const float4 iv = *(const float4*)&inv_std[j4 * 4];
  float4 o;
  o.x = (q + c2.x * x.x + c3 - m.x) * iv.x;
  o.y = (q + c2.y * x.y + c3 - m.y) * iv.y;
  o.z = (q + c2.z * x.z + c3 - m.z) * iv.z;
  o.w = (q + c2.w * x.w + c3 - m.w) * iv.w;
  *(float4*)&out[(size_t)idx * 4] = o;
}

extern "C" void kernel_launch(void* const* d_in, const int* in_sizes, int n_in,
                              void* d_out, int out_size, void* d_ws, size_t ws_size,
                              hipStream_t stream) {
  const float* X  = (const float*)d_in[0];
  const float* C1 = (const float*)d_in[1];
  const float* C2 = (const float*)d_in[2];
  const float* C3 = (const float*)d_in[3];
  float* out = (float*)d_out;

  // Workspace layout (needs ~272 KB):
  char* ws = (char*)d_ws;
  float*  quad    = (float*)ws;                                   // N floats
  float*  colS1   = (float*)(ws + (size_t)NROWS * 4);             // K
  float*  colS2   = colS1 + KDIM;                                 // K
  float*  colS3   = colS2 + KDIM;                                 // K
  double* qsums   = (double*)(ws + (size_t)NROWS * 4 + 3 * KDIM * 4);  // 2 doubles (offset 268288, 8-aligned)
  float*  mean    = (float*)(ws + (size_t)NROWS * 4 + 3 * KDIM * 4 + 16);
  float*  inv_std = mean + KDIM;

  // zero the atomic accumulators (colS1..colS3 + qsums are contiguous)
  hipMemsetAsync(colS1, 0, 3 * KDIM * 4 + 16, stream);

  quad_kernel<<<NROWS / BM, 256, 0, stream>>>(X, C1, quad);
  colstats_kernel<<<256, 256, 0, stream>>>(X, quad, colS1, colS2, colS3, qsums);
  finalize_kernel<<<2, 256, 0, stream>>>(colS1, colS2, colS3, qsums, C2, C3, mean, inv_std);
  normalize_kernel<<<(NROWS * (KDIM / 4)) / 256, 256, 0, stream>>>(
      X, quad, C2, C3, mean, inv_std, out);
}

// Round 3
// 282.780 us; speedup vs baseline: 1.6565x; 1.6565x over previous
//
#include <hip/hip_runtime.h>

#define NROWS 65536
#define KDIM  512
constexpr float BN_EPS = 1e-5f;

using short8 = __attribute__((ext_vector_type(8))) short;
using f32x4  = __attribute__((ext_vector_type(4))) float;

#define BM 128
#define BJ 128
#define BK 32

// Split fp32 x into bf16 hi (truncation) + bf16 lo (truncated remainder).
__device__ __forceinline__ unsigned pack2(float x0, float x1, float& r0, float& r1) {
  unsigned u0 = __float_as_uint(x0), u1 = __float_as_uint(x1);
  r0 = x0 - __uint_as_float(u0 & 0xFFFF0000u);
  r1 = x1 - __uint_as_float(u1 & 0xFFFF0000u);
  return (u0 >> 16) | (u1 & 0xFFFF0000u);
}

__device__ __forceinline__ void cvt8s(const float* e, int4& hi, int4& lo) {
  float r[8];
  hi.x = (int)pack2(e[0], e[1], r[0], r[1]);
  hi.y = (int)pack2(e[2], e[3], r[2], r[3]);
  hi.z = (int)pack2(e[4], e[5], r[4], r[5]);
  hi.w = (int)pack2(e[6], e[7], r[6], r[7]);
  lo.x = (int)((__float_as_uint(r[0]) >> 16) | (__float_as_uint(r[1]) & 0xFFFF0000u));
  lo.y = (int)((__float_as_uint(r[2]) >> 16) | (__float_as_uint(r[3]) & 0xFFFF0000u));
  lo.z = (int)((__float_as_uint(r[4]) >> 16) | (__float_as_uint(r[5]) & 0xFFFF0000u));
  lo.w = (int)((__float_as_uint(r[6]) >> 16) | (__float_as_uint(r[7]) & 0xFFFF0000u));
}

// quad[n] = x_n^T C1 x_n via split-bf16 MFMA (3 passes: HH + LH + HL),
// fused with per-block column-stat partials (colS1/S2/S3, qsums).
__global__ __launch_bounds__(256)
void quad_kernel(const float* __restrict__ X, const float* __restrict__ C1,
                 float* __restrict__ quad,
                 float* __restrict__ colS1, float* __restrict__ colS2,
                 float* __restrict__ colS3, double* __restrict__ qsums) {
  // chunk-swizzled layouts: element (row, k0+8g+i) lives at
  // [row*BK + (g ^ ((row>>2)&3))*8 + i]  (shorts). 16B-aligned b128 chunks.
  __shared__ short XsH[BM * BK], XsL[BM * BK];
  __shared__ short BsH[BJ * BK], BsL[BJ * BK];
  __shared__ float qPart[2][BM];   // per-wj-half row partial sums
  __shared__ float qLds[BM];

  const int tid  = threadIdx.x;
  const int lane = tid & 63;
  const int wid  = tid >> 6;
  const int wm   = wid >> 1;          // wave row-block (0..1)
  const int wj   = wid & 1;           // wave col-block (0..1)
  const int g    = lane >> 4;         // k-group 0..3
  const int lr   = lane & 15;
  const int r0   = blockIdx.x * BM;

  // staging assignments
  const int srow  = tid >> 1;         // X stage row 0..127
  const int shalf = tid & 1;          // X stage k-half
  const int bj    = tid & 127;        // B stage col 0..127
  const int bkg2  = (tid >> 7) * 2;   // B stage k-chunk base (0 or 2)

  float qacc[16] = {};                // [rf*4 + p] partial row sums (this wave's wj half)

  for (int jt = 0; jt < KDIM / BJ; ++jt) {
    const int j0 = jt * BJ;
    f32x4 acc[4][4];
    #pragma unroll
    for (int rf = 0; rf < 4; ++rf)
      #pragma unroll
      for (int cf = 0; cf < 4; ++cf)
        acc[rf][cf] = (f32x4){0.f, 0.f, 0.f, 0.f};

    for (int kt = 0; kt < KDIM / BK; ++kt) {
      const int k0 = kt * BK;
      // ---- stage X tile: fp32 -> bf16 hi/lo ----
      {
        const float* xp = X + (size_t)(r0 + srow) * KDIM + k0 + shalf * 16;
        float e0[8], e1[8];
        const float4 va = *(const float4*)(xp);
        const float4 vb = *(const float4*)(xp + 4);
        const float4 vc = *(const float4*)(xp + 8);
        const float4 vd = *(const float4*)(xp + 12);
        e0[0]=va.x; e0[1]=va.y; e0[2]=va.z; e0[3]=va.w;
        e0[4]=vb.x; e0[5]=vb.y; e0[6]=vb.z; e0[7]=vb.w;
        e1[0]=vc.x; e1[1]=vc.y; e1[2]=vc.z; e1[3]=vc.w;
        e1[4]=vd.x; e1[5]=vd.y; e1[6]=vd.z; e1[7]=vd.w;
        int4 h0, l0, h1, l1;
        cvt8s(e0, h0, l0);
        cvt8s(e1, h1, l1);
        const int sw = (srow >> 2) & 3;
        const int c0 = (shalf * 2 + 0) ^ sw;
        const int c1 = (shalf * 2 + 1) ^ sw;
        *(int4*)&XsH[srow * BK + c0 * 8] = h0;
        *(int4*)&XsL[srow * BK + c0 * 8] = l0;
        *(int4*)&XsH[srow * BK + c1 * 8] = h1;
        *(int4*)&XsL[srow * BK + c1 * 8] = l1;
      }
      // ---- stage C1 tile (k-major per thread; coalesced across lanes) ----
      {
        const int bsw = (bj >> 2) & 3;
        #pragma unroll
        for (int s = 0; s < 2; ++s) {
          const int kg = bkg2 + s;
          const float* cp = C1 + (size_t)(k0 + kg * 8) * KDIM + j0 + bj;
          float e[8];
          #pragma unroll
          for (int i = 0; i < 8; ++i) e[i] = cp[(size_t)i * KDIM];
          int4 hi, lo;
          cvt8s(e, hi, lo);
          const int cc = kg ^ bsw;
          *(int4*)&BsH[bj * BK + cc * 8] = hi;
          *(int4*)&BsL[bj * BK + cc * 8] = lo;
        }
      }
      __syncthreads();
      // ---- fragments + MFMA ----
      short8 aH[4], aL[4], bH[4], bL[4];
      #pragma unroll
      for (int rf = 0; rf < 4; ++rf) {
        const int row = wm * 64 + rf * 16 + lr;
        const int ch = g ^ ((row >> 2) & 3);
        aH[rf] = *(const short8*)&XsH[row * BK + ch * 8];
        aL[rf] = *(const short8*)&XsL[row * BK + ch * 8];
      }
      #pragma unroll
      for (int cf = 0; cf < 4; ++cf) {
        const int col = wj * 64 + cf * 16 + lr;
        const int ch = g ^ ((col >> 2) & 3);
        bH[cf] = *(const short8*)&BsH[col * BK + ch * 8];
        bL[cf] = *(const short8*)&BsL[col * BK + ch * 8];
      }
      #pragma unroll
      for (int rf = 0; rf < 4; ++rf)
        #pragma unroll
        for (int cf = 0; cf < 4; ++cf) {
          acc[rf][cf] = __builtin_amdgcn_mfma_f32_16x16x32_bf16(aH[rf], bH[cf], acc[rf][cf], 0, 0, 0);
          acc[rf][cf] = __builtin_amdgcn_mfma_f32_16x16x32_bf16(aL[rf], bH[cf], acc[rf][cf], 0, 0, 0);
          acc[rf][cf] = __builtin_amdgcn_mfma_f32_16x16x32_bf16(aH[rf], bL[cf], acc[rf][cf], 0, 0, 0);
        }
      __syncthreads();
    }
    // ---- epilogue: qacc += Y[row, j] * X[row, j] for this wave's wj half ----
    #pragma unroll
    for (int rf = 0; rf < 4; ++rf)
      #pragma unroll
      for (int p = 0; p < 4; ++p) {
        const int grow = r0 + wm * 64 + rf * 16 + g * 4 + p;
        const float* xr = X + (size_t)grow * KDIM + j0 + wj * 64;
        float s = 0.f;
        #pragma unroll
        for (int cf = 0; cf < 4; ++cf)
          s += acc[rf][cf][p] * xr[cf * 16 + lr];
        qacc[rf * 4 + p] += s;
      }
  }
  // ---- reduce qacc across the 16 lanes of each lane-group; stash per-wj partials ----
  #pragma unroll
  for (int s = 0; s < 16; ++s) {
    float q = qacc[s];
    q += __shfl_xor(q, 1, 64);
    q += __shfl_xor(q, 2, 64);
    q += __shfl_xor(q, 4, 64);
    q += __shfl_xor(q, 8, 64);
    if (lr == 0) {
      const int row = wm * 64 + (s >> 2) * 16 + g * 4 + (s & 3);
      qPart[wj][row] = q;     // each (wm,wj) wave owns distinct [wj][row] slots
    }
  }
  __syncthreads();
  // ---- combine the two wj halves (the round-2 bug: these were never summed) ----
  if (tid < BM) {
    const float q = qPart[0][tid] + qPart[1][tid];
    quad[r0 + tid] = q;
    qLds[tid] = q;
  }
  __syncthreads();
  // ---- fused column stats over the (cache-hot) X panel ----
  {
    float s1a = 0.f, s2a = 0.f, s3a = 0.f, s1b = 0.f, s2b = 0.f, s3b = 0.f;
    for (int r = 0; r < BM; ++r) {
      const float q = qLds[r];
      const float* xp = X + (size_t)(r0 + r) * KDIM + tid;
      const float x0 = xp[0];
      const float x1 = xp[256];
      s1a += x0; s2a += x0 * x0; s3a += q * x0;
      s1b += x1; s2b += x1 * x1; s3b += q * x1;
    }
    atomicAdd(&colS1[tid], s1a); atomicAdd(&colS1[tid + 256], s1b);
    atomicAdd(&colS2[tid], s2a); atomicAdd(&colS2[tid + 256], s2b);
    atomicAdd(&colS3[tid], s3a); atomicAdd(&colS3[tid + 256], s3b);
  }
  if (tid < BM) {
    double q = (double)qLds[tid];
    double q2 = q * q;
    #pragma unroll
    for (int m = 1; m < 64; m <<= 1) {
      q  += __shfl_xor(q,  m, 64);
      q2 += __shfl_xor(q2, m, 64);
    }
    if ((tid & 63) == 0) { atomicAdd(&qsums[0], q); atomicAdd(&qsums[1], q2); }
  }
}

// ---------------- finalize per-feature mean / inv_std ----------------
__global__ void finalize_kernel(const float* __restrict__ colS1, const float* __restrict__ colS2,
                                const float* __restrict__ colS3, const double* __restrict__ qsums,
                                const float* __restrict__ C2, const float* __restrict__ C3,
                                float* __restrict__ mean, float* __restrict__ inv_std) {
  const int k = blockIdx.x * blockDim.x + threadIdx.x;
  if (k >= KDIM) return;
  const double invN = 1.0 / (double)NROWS;
  const double meanQ = qsums[0] * invN;
  const double varQ  = qsums[1] * invN - meanQ * meanQ;
  const float meanX = colS1[k] * (float)invN;
  const float varX  = colS2[k] * (float)invN - meanX * meanX;
  const float covQX = colS3[k] * (float)invN - (float)meanQ * meanX;
  const float c2 = C2[k];
  const float c3 = C3[0];
  const float m = (float)meanQ + c2 * meanX + c3;
  const float v = (float)varQ + c2 * c2 * varX + 2.0f * c2 * covQX;
  mean[k] = m;
  inv_std[k] = 1.0f / sqrtf(v + BN_EPS);
}

// ---------------- normalize + write ----------------
__global__ __launch_bounds__(256)
void normalize_kernel(const float* __restrict__ X, const float* __restrict__ quad,
                      const float* __restrict__ C2, const float* __restrict__ C3,
                      const float* __restrict__ mean, const float* __restrict__ inv_std,
                      float* __restrict__ out) {
  const int idx = blockIdx.x * blockDim.x + threadIdx.x;  // float4 index
  const int n = idx >> 7;                                 // KDIM/4 = 128 float4/row
  const int j4 = idx & 127;
  const float q = quad[n];
  const float c3 = C3[0];
  const float4 x  = *(const float4*)&X[(size_t)idx * 4];
  const float4 c2 = *(const float4*)&C2[j4 * 4];
  const float4 m  = *(const float4*)&mean[j4 * 4];
  const float4 iv = *(const float4*)&inv_std[j4 * 4];
  float4 o;
  o.x = (q + c2.x * x.x + c3 - m.x) * iv.x;
  o.y = (q + c2.y * x.y + c3 - m.y) * iv.y;
  o.z = (q + c2.z * x.z + c3 - m.z) * iv.z;
  o.w = (q + c2.w * x.w + c3 - m.w) * iv.w;
  *(float4*)&out[(size_t)idx * 4] = o;
}

extern "C" void kernel_launch(void* const* d_in, const int* in_sizes, int n_in,
                              void* d_out, int out_size, void* d_ws, size_t ws_size,
                              hipStream_t stream) {
  const float* X  = (const float*)d_in[0];
  const float* C1 = (const float*)d_in[1];
  const float* C2 = (const float*)d_in[2];
  const float* C3 = (const float*)d_in[3];
  float* out = (float*)d_out;

  char* ws = (char*)d_ws;
  float*  quad    = (float*)ws;                                        // N floats
  float*  colS1   = (float*)(ws + (size_t)NROWS * 4);                  // K
  float*  colS2   = colS1 + KDIM;                                      // K
  float*  colS3   = colS2 + KDIM;                                      // K
  double* qsums   = (double*)(ws + (size_t)NROWS * 4 + 3 * KDIM * 4);  // 2 doubles
  float*  mean    = (float*)(ws + (size_t)NROWS * 4 + 3 * KDIM * 4 + 16);
  float*  inv_std = mean + KDIM;

  hipMemsetAsync(colS1, 0, 3 * KDIM * 4 + 16, stream);

  quad_kernel<<<NROWS / BM, 256, 0, stream>>>(X, C1, quad, colS1, colS2, colS3, qsums);
  finalize_kernel<<<2, 256, 0, stream>>>(colS1, colS2, colS3, qsums, C2, C3, mean, inv_std);
  normalize_kernel<<<(NROWS * (KDIM / 4)) / 256, 256, 0, stream>>>(
      X, quad, C2, C3, mean, inv_std, out);
}

// Round 4
// 255.039 us; speedup vs baseline: 1.8367x; 1.1088x over previous
//
#include <hip/hip_runtime.h>

#define NROWS 65536
#define KDIM  512
constexpr float BN_EPS = 1e-5f;

using short8 = __attribute__((ext_vector_type(8))) short;
using f32x4  = __attribute__((ext_vector_type(4))) float;

#define BM 128

// Split fp32 -> bf16 hi (truncate) + bf16 lo (truncated remainder).
__device__ __forceinline__ void cvt8(const float4& a, const float4& b, short8& hi, short8& lo) {
  const float e[8] = {a.x, a.y, a.z, a.w, b.x, b.y, b.z, b.w};
  #pragma unroll
  for (int i = 0; i < 8; ++i) {
    const unsigned u = __float_as_uint(e[i]);
    const float r = e[i] - __uint_as_float(u & 0xFFFF0000u);
    hi[i] = (short)(u >> 16);
    lo[i] = (short)(__float_as_uint(r) >> 16);
  }
}

// ---------------- prep: C1 -> fragment-tiled bf16 hi/lo ----------------
// c1t entry e = kg*512 + col (kg = global k-group 0..63) holds 8 shorts:
// C1[kg*8 + i][col], i = 0..7. A lane's B-fragment is ONE contiguous entry.
__global__ __launch_bounds__(256)
void prep_c1(const float* __restrict__ C1, short8* __restrict__ c1tH,
             short8* __restrict__ c1tL) {
  const int e   = blockIdx.x * 256 + threadIdx.x;   // 0..32767
  const int col = e & 511;
  const int kg  = e >> 9;
  short8 hi, lo;
  #pragma unroll
  for (int i = 0; i < 8; ++i) {
    const float x = C1[(size_t)(kg * 8 + i) * KDIM + col];   // coalesced across lanes
    const unsigned u = __float_as_uint(x);
    const float r = x - __uint_as_float(u & 0xFFFF0000u);
    hi[i] = (short)(u >> 16);
    lo[i] = (short)(__float_as_uint(r) >> 16);
  }
  c1tH[e] = hi;
  c1tL[e] = lo;
}

// ---------------- quad: zero-barrier register-direct MFMA ----------------
// quad[n] = x_n^T C1 x_n  (split-bf16, 3 MFMA passes: HH + LH + HL),
// fused with column-stat partials. No LDS / no __syncthreads in the main loop.
__global__ __launch_bounds__(256)
void quad_kernel(const float* __restrict__ X,
                 const short8* __restrict__ c1tH, const short8* __restrict__ c1tL,
                 float* __restrict__ quad,
                 float* __restrict__ colS1, float* __restrict__ colS2,
                 float* __restrict__ colS3, double* __restrict__ qsums) {
  __shared__ float qPart[2][BM];
  __shared__ float qLds[BM];

  const int tid  = threadIdx.x;
  const int lane = tid & 63;
  const int wid  = tid >> 6;
  const int wm   = wid >> 1;          // wave row-half (0..1)
  const int wj   = wid & 1;           // wave col-half (0..1)
  const int g    = lane >> 4;         // k-group 0..3
  const int lr   = lane & 15;
  const int r0   = blockIdx.x * BM;

  float qacc[16] = {};                // [rf*4 + p] row partials (this wave's wj half)

  for (int jt = 0; jt < 4; ++jt) {
    const int j0 = jt * 128;
    f32x4 acc[4][4];
    #pragma unroll
    for (int rf = 0; rf < 4; ++rf)
      #pragma unroll
      for (int cf = 0; cf < 4; ++cf)
        acc[rf][cf] = (f32x4){0.f, 0.f, 0.f, 0.f};

    for (int kt = 0; kt < 16; ++kt) {
      // B fragments: direct from pre-tiled global (L2-resident), 16B/lane
      const int ebase = (kt * 4 + g) * KDIM + j0 + wj * 64 + lr;
      short8 bH[4], bL[4];
      #pragma unroll
      for (int cf = 0; cf < 4; ++cf) {
        bH[cf] = c1tH[ebase + cf * 16];
        bL[cf] = c1tL[ebase + cf * 16];
      }
      // A raw: 32B per lane, rows wm*64+rf*16+lr, k-slice kt*32+g*8
      float4 xr0[4], xr1[4];
      #pragma unroll
      for (int rf = 0; rf < 4; ++rf) {
        const float* xp = X + (size_t)(r0 + wm * 64 + rf * 16 + lr) * KDIM + kt * 32 + g * 8;
        xr0[rf] = *(const float4*)xp;
        xr1[rf] = *(const float4*)(xp + 4);
      }
      #pragma unroll
      for (int rf = 0; rf < 4; ++rf) {
        short8 aH, aL;
        cvt8(xr0[rf], xr1[rf], aH, aL);
        #pragma unroll
        for (int cf = 0; cf < 4; ++cf) {
          acc[rf][cf] = __builtin_amdgcn_mfma_f32_16x16x32_bf16(aH, bH[cf], acc[rf][cf], 0, 0, 0);
          acc[rf][cf] = __builtin_amdgcn_mfma_f32_16x16x32_bf16(aL, bH[cf], acc[rf][cf], 0, 0, 0);
          acc[rf][cf] = __builtin_amdgcn_mfma_f32_16x16x32_bf16(aH, bL[cf], acc[rf][cf], 0, 0, 0);
        }
      }
    }
    // epilogue: qacc += Y[row, j] * X[row, j] for this wave's wj half
    #pragma unroll
    for (int rf = 0; rf < 4; ++rf)
      #pragma unroll
      for (int p = 0; p < 4; ++p) {
        const int grow = r0 + wm * 64 + rf * 16 + g * 4 + p;
        const float* xr = X + (size_t)grow * KDIM + j0 + wj * 64;
        float s = 0.f;
        #pragma unroll
        for (int cf = 0; cf < 4; ++cf)
          s += acc[rf][cf][p] * xr[cf * 16 + lr];
        qacc[rf * 4 + p] += s;
      }
  }
  // reduce across the 16 lanes of each lane-group; stash per-wj partials
  #pragma unroll
  for (int s = 0; s < 16; ++s) {
    float q = qacc[s];
    q += __shfl_xor(q, 1, 64);
    q += __shfl_xor(q, 2, 64);
    q += __shfl_xor(q, 4, 64);
    q += __shfl_xor(q, 8, 64);
    if (lr == 0) {
      const int row = wm * 64 + (s >> 2) * 16 + g * 4 + (s & 3);
      qPart[wj][row] = q;
    }
  }
  __syncthreads();
  if (tid < BM) {
    const float q = qPart[0][tid] + qPart[1][tid];
    quad[r0 + tid] = q;
    qLds[tid] = q;
  }
  __syncthreads();
  // fused column stats over the (cache-hot) X panel
  {
    float s1a = 0.f, s2a = 0.f, s3a = 0.f, s1b = 0.f, s2b = 0.f, s3b = 0.f;
    for (int r = 0; r < BM; ++r) {
      const float q = qLds[r];
      const float* xp = X + (size_t)(r0 + r) * KDIM + tid;
      const float x0 = xp[0];
      const float x1 = xp[256];
      s1a += x0; s2a += x0 * x0; s3a += q * x0;
      s1b += x1; s2b += x1 * x1; s3b += q * x1;
    }
    atomicAdd(&colS1[tid], s1a); atomicAdd(&colS1[tid + 256], s1b);
    atomicAdd(&colS2[tid], s2a); atomicAdd(&colS2[tid + 256], s2b);
    atomicAdd(&colS3[tid], s3a); atomicAdd(&colS3[tid + 256], s3b);
  }
  if (tid < BM) {
    double q = (double)qLds[tid];
    double q2 = q * q;
    #pragma unroll
    for (int m = 1; m < 64; m <<= 1) {
      q  += __shfl_xor(q,  m, 64);
      q2 += __shfl_xor(q2, m, 64);
    }
    if ((tid & 63) == 0) { atomicAdd(&qsums[0], q); atomicAdd(&qsums[1], q2); }
  }
}

// ---------------- finalize per-feature mean / inv_std ----------------
__global__ void finalize_kernel(const float* __restrict__ colS1, const float* __restrict__ colS2,
                                const float* __restrict__ colS3, const double* __restrict__ qsums,
                                const float* __restrict__ C2, const float* __restrict__ C3,
                                float* __restrict__ mean, float* __restrict__ inv_std) {
  const int k = blockIdx.x * blockDim.x + threadIdx.x;
  if (k >= KDIM) return;
  const double invN = 1.0 / (double)NROWS;
  const double meanQ = qsums[0] * invN;
  const double varQ  = qsums[1] * invN - meanQ * meanQ;
  const float meanX = colS1[k] * (float)invN;
  const float varX  = colS2[k] * (float)invN - meanX * meanX;
  const float covQX = colS3[k] * (float)invN - (float)meanQ * meanX;
  const float c2 = C2[k];
  const float c3 = C3[0];
  const float m = (float)meanQ + c2 * meanX + c3;
  const float v = (float)varQ + c2 * c2 * varX + 2.0f * c2 * covQX;
  mean[k] = m;
  inv_std[k] = 1.0f / sqrtf(v + BN_EPS);
}

// ---------------- normalize + write ----------------
__global__ __launch_bounds__(256)
void normalize_kernel(const float* __restrict__ X, const float* __restrict__ quad,
                      const float* __restrict__ C2, const float* __restrict__ C3,
                      const float* __restrict__ mean, const float* __restrict__ inv_std,
                      float* __restrict__ out) {
  const int idx = blockIdx.x * blockDim.x + threadIdx.x;  // float4 index
  const int n = idx >> 7;
  const int j4 = idx & 127;
  const float q = quad[n];
  const float c3 = C3[0];
  const float4 x  = *(const float4*)&X[(size_t)idx * 4];
  const float4 c2 = *(const float4*)&C2[j4 * 4];
  const float4 m  = *(const float4*)&mean[j4 * 4];
  const float4 iv = *(const float4*)&inv_std[j4 * 4];
  float4 o;
  o.x = (q + c2.x * x.x + c3 - m.x) * iv.x;
  o.y = (q + c2.y * x.y + c3 - m.y) * iv.y;
  o.z = (q + c2.z * x.z + c3 - m.z) * iv.z;
  o.w = (q + c2.w * x.w + c3 - m.w) * iv.w;
  *(float4*)&out[(size_t)idx * 4] = o;
}

extern "C" void kernel_launch(void* const* d_in, const int* in_sizes, int n_in,
                              void* d_out, int out_size, void* d_ws, size_t ws_size,
                              hipStream_t stream) {
  const float* X  = (const float*)d_in[0];
  const float* C1 = (const float*)d_in[1];
  const float* C2 = (const float*)d_in[2];
  const float* C3 = (const float*)d_in[3];
  float* out = (float*)d_out;

  char* ws = (char*)d_ws;
  float*  quad    = (float*)ws;                                        // 256 KB
  float*  colS1   = (float*)(ws + (size_t)NROWS * 4);                  // K
  float*  colS2   = colS1 + KDIM;
  float*  colS3   = colS2 + KDIM;
  double* qsums   = (double*)(ws + (size_t)NROWS * 4 + 3 * KDIM * 4);  // 2 doubles
  float*  mean    = (float*)(ws + (size_t)NROWS * 4 + 3 * KDIM * 4 + 16);
  float*  inv_std = mean + KDIM;
  short8* c1tH    = (short8*)(ws + 276480);                            // 512 KB (16B aligned)
  short8* c1tL    = (short8*)(ws + 276480 + 524288);                   // 512 KB

  hipMemsetAsync(colS1, 0, 3 * KDIM * 4 + 16, stream);

  prep_c1<<<128, 256, 0, stream>>>(C1, c1tH, c1tL);
  quad_kernel<<<NROWS / BM, 256, 0, stream>>>(X, c1tH, c1tL, quad,
                                              colS1, colS2, colS3, qsums);
  finalize_kernel<<<2, 256, 0, stream>>>(colS1, colS2, colS3, qsums, C2, C3, mean, inv_std);
  normalize_kernel<<<(NROWS * (KDIM / 4)) / 256, 256, 0, stream>>>(
      X, quad, C2, C3, mean, inv_std, out);
}